// Round 1
// baseline (127.130 us; speedup 1.0000x reference)
//
#include <hip/hip_runtime.h>

#define MAX_ITEMS 100000
constexpr int B = 4096;
constexpr int D = 512;
constexpr long long ACT_ELEMS  = (long long)B * D;              // 2097152
constexpr long long HIST_ELEMS = (long long)(MAX_ITEMS + 1) * D; // 51200512
// d_out layout: [0, ACT) activations, [ACT] loss, [ACT+1, ACT+1+HIST) new_history

// ---------------------------------------------------------------------------
// Kernel 1: copy activations -> out[0..) (both 16B aligned) and
//           history -> out[ACT+1..)  (dst misaligned by 4B: align on DST,
//           scalar-load the src, float4-store the dst)
// ---------------------------------------------------------------------------
__global__ void copy_kernel(const float* __restrict__ act,
                            const float* __restrict__ hist,
                            float* __restrict__ out) {
    constexpr long long NA4 = ACT_ELEMS / 4;          // 524288 float4 units
    constexpr long long NG  = (HIST_ELEMS - 3) / 4;   // 12800127 groups (1 tail elem)
    const long long total = NA4 + NG;
    float* __restrict__ outh = out + ACT_ELEMS + 1;   // new_history base

    for (long long u = (long long)blockIdx.x * blockDim.x + threadIdx.x;
         u < total;
         u += (long long)gridDim.x * blockDim.x) {
        if (u < NA4) {
            reinterpret_cast<float4*>(out)[u] =
                reinterpret_cast<const float4*>(act)[u];
        } else {
            const long long g  = u - NA4;
            const long long sb = 3 + 4 * g;           // src float index
            float4 v;
            v.x = hist[sb + 0];
            v.y = hist[sb + 1];
            v.z = hist[sb + 2];
            v.w = hist[sb + 3];
            // dst float index ACT+1+3+4g -> byte (2097156+4g)*4, 16B aligned
            *reinterpret_cast<float4*>(outh + sb) = v;
        }
    }
    if (blockIdx.x == 0 && threadIdx.x == 0) {
        outh[0] = hist[0];
        outh[1] = hist[1];
        outh[2] = hist[2];
        outh[HIST_ELEMS - 1] = hist[HIST_ELEMS - 1];
    }
}

// ---------------------------------------------------------------------------
// Kernel 2: one wave per sample. Gather old row (from ORIGINAL history input),
// compute sum of squared diff (wave-reduced -> partial[s]), and scatter the
// EMA update into new_history with atomicAdd (duplicates must accumulate).
// ---------------------------------------------------------------------------
__global__ void update_kernel(const float* __restrict__ act,
                              const float* __restrict__ hist,
                              const int* __restrict__ samples,
                              float* __restrict__ out,
                              float* __restrict__ partial) {
    const int s    = blockIdx.x;
    const int lane = threadIdx.x; // 0..63, one wave per block

    const int id = samples[s];
    const bool active = (id > 0) && (id < MAX_ITEMS);

    float sumsq = 0.0f;
    if (active) {
        const float* __restrict__ arow = act  + (long long)s  * D;
        const float* __restrict__ orow = hist + (long long)id * D;
        float* __restrict__ newh = out + ACT_ELEMS + 1 + (long long)id * D;

        #pragma unroll
        for (int k = 0; k < 2; ++k) {
            const int e = (lane + k * 64) * 4; // 128 float4 per row, 2 per lane
            const float4 a = *reinterpret_cast<const float4*>(arow + e);
            const float4 o = *reinterpret_cast<const float4*>(orow + e);
            const float dx = a.x - o.x;
            const float dy = a.y - o.y;
            const float dz = a.z - o.z;
            const float dw = a.w - o.w;
            sumsq += dx * dx + dy * dy + dz * dz + dw * dw;
            // new_history[id] += -(1-0.9)*(old-act) = +0.1*(act-old)
            atomicAdd(newh + e + 0, 0.1f * dx);
            atomicAdd(newh + e + 1, 0.1f * dy);
            atomicAdd(newh + e + 2, 0.1f * dz);
            atomicAdd(newh + e + 3, 0.1f * dw);
        }
    }
    // full-wave butterfly reduce (64 lanes)
    #pragma unroll
    for (int off = 32; off; off >>= 1)
        sumsq += __shfl_down(sumsq, off);
    if (lane == 0) partial[s] = sumsq; // masked rows contribute exactly 0
}

// ---------------------------------------------------------------------------
// Kernel 3: deterministic single-block reduction of 4096 partials -> loss.
// ---------------------------------------------------------------------------
__global__ void loss_kernel(const float* __restrict__ partial,
                            const int* __restrict__ iters,
                            float* __restrict__ out) {
    __shared__ float sm[256];
    const int t = threadIdx.x;
    float s = 0.0f;
    for (int i = t; i < B; i += 256) s += partial[i]; // fixed order: 16 adds
    sm[t] = s;
    __syncthreads();
    #pragma unroll
    for (int w = 128; w; w >>= 1) {
        if (t < w) sm[t] += sm[t + w];
        __syncthreads();
    }
    if (t == 0) {
        const float it = (float)iters[0];
        const float wr = (float)(1.0 / 1000.0)   * it;
        const float cr = (float)(1.0 / 100000.0) * it;
        const float weight = 0.1f * wr / (1.0f + wr) / (1.0f + cr);
        out[ACT_ELEMS] = (sm[0] / (float)D / (float)B) * weight;
    }
}

extern "C" void kernel_launch(void* const* d_in, const int* in_sizes, int n_in,
                              void* d_out, int out_size, void* d_ws, size_t ws_size,
                              hipStream_t stream) {
    const float* act     = (const float*)d_in[0];
    const float* hist    = (const float*)d_in[1];
    const int*   samples = (const int*)d_in[2];
    const int*   iters   = (const int*)d_in[3];
    float* out     = (float*)d_out;
    float* partial = (float*)d_ws; // needs B*4 = 16 KiB of workspace

    copy_kernel<<<2048, 256, 0, stream>>>(act, hist, out);
    update_kernel<<<B, 64, 0, stream>>>(act, hist, samples, out, partial);
    loss_kernel<<<1, 256, 0, stream>>>(partial, iters, out);
}